// Round 5
// baseline (11.183 us; speedup 1.0000x reference)
//
#include <hip/hip_runtime.h>

#define BATCH 512
#define DIMS  2048
#define SPLIT 4
#define SEG   (DIMS / SPLIT)   // 512 floats per segment

// Kernel 1: 2048 WGs (4 per sample), each one wave computing a quarter-row
// partial of ||f_b - c_{t_b}||^2. partial[b*4+j], no clip here.
__global__ __launch_bounds__(64) void center_dist_partial(
        const float* __restrict__ features,
        const float* __restrict__ centers,
        const int* __restrict__ targets,
        float* __restrict__ partials) {
    const int w = blockIdx.x;
    const int b = w >> 2;
    const int j = w & 3;
    const int t = targets[b];
    const float4* f = reinterpret_cast<const float4*>(features + (size_t)b * DIMS + j * SEG) + threadIdx.x;
    const float4* c = reinterpret_cast<const float4*>(centers  + (size_t)t * DIMS + j * SEG) + threadIdx.x;

    // SEG/4 = 128 float4 over 64 lanes -> 2 per lane per array. All 4 loads
    // issued before any math.
    float4 f0 = f[0], f1 = f[64];
    float4 c0 = c[0], c1 = c[64];

    float dx = f0.x - c0.x, dy = f0.y - c0.y, dz = f0.z - c0.z, dw = f0.w - c0.w;
    float acc = dx * dx + dy * dy + dz * dz + dw * dw;
    dx = f1.x - c1.x; dy = f1.y - c1.y; dz = f1.z - c1.z; dw = f1.w - c1.w;
    acc += dx * dx + dy * dy + dz * dz + dw * dw;

    #pragma unroll
    for (int off = 32; off > 0; off >>= 1) acc += __shfl_down(acc, off, 64);

    if (threadIdx.x == 0)
        partials[w] = acc;
}

// Kernel 2: single wave. Each sample's 4 partials are one contiguous float4:
// dist[b] = clip(sum(partial4[b])); out = mean(dist). Fixed order -> deterministic.
__global__ __launch_bounds__(64) void mean_kernel(
        const float* __restrict__ partials,
        float* __restrict__ out) {
    const float4* p = reinterpret_cast<const float4*>(partials);  // [BATCH] float4
    float acc = 0.f;
    #pragma unroll
    for (int i = 0; i < BATCH / 64; ++i) {            // 8 samples per lane
        float4 v = p[threadIdx.x + i * 64];
        float d = (v.x + v.y) + (v.z + v.w);
        d = fminf(fmaxf(d, 1e-12f), 1e12f);
        acc += d;
    }

    #pragma unroll
    for (int off = 32; off > 0; off >>= 1) acc += __shfl_down(acc, off, 64);

    if (threadIdx.x == 0)
        out[0] = acc * (1.0f / BATCH);
}

extern "C" void kernel_launch(void* const* d_in, const int* in_sizes, int n_in,
                              void* d_out, int out_size, void* d_ws, size_t ws_size,
                              hipStream_t stream) {
    const float* features = (const float*)d_in[0];
    const float* centers  = (const float*)d_in[1];
    const int*   targets  = (const int*)d_in[2];
    float* out      = (float*)d_out;
    float* partials = (float*)d_ws;   // 8 KB scratch

    center_dist_partial<<<BATCH * SPLIT, 64, 0, stream>>>(features, centers, targets, partials);
    mean_kernel<<<1, 64, 0, stream>>>(partials, out);
}